// Round 1
// baseline (1186.607 us; speedup 1.0000x reference)
//
#include <hip/hip_runtime.h>
#include <hip/hip_bf16.h>
#include <stdint.h>

typedef uint16_t u16;
typedef uint32_t u32;
typedef uint64_t u64;
typedef unsigned char u8;

#define TT 16384
#define ZZ 4096
#define EE 65536
#define LBLK 64
#define NBLK 256          // TT / LBLK
#define ADJ_STRIDE 80     // u16 entries per adjacency row (max degree ~60 w.h.p.)
#define PEN 10.0f

// ---- ws layout (bytes) ----
#define WS_BITS   0x000000   // u32[4096*128]  2 MB   adjacency bitmask
#define WS_GMKEY  0x200000   // u64[16384]     128 KB packed global (max,argmax) per row
#define WS_DEG    0x220000   // u32[4096]
#define WS_ADJL   0x224000   // u16[4096*80]   640 KB CSR lists
#define WS_CVEC   0x2C4000   // f32[128]
#define WS_WVEC   0x2C4200   // f32[128]
#define WS_H2     0x2C4400   // f32[16384*64]  4 MB
#define WS_G      0x6C4400   // u16[256*4096]  2 MB   per-block composed maps
#define WS_H      0x8C4400   // u16[16*4096]   128 KB super maps
#define WS_SB     0x8E4400   // u32[256]       block-start states
#define WS_CUR    0x8E4800   // u32[16384]     cur[t]

// monotone (value, min-index) packing: bigger key == larger value, then smaller z
__device__ __forceinline__ unsigned long long packkey(float v, u32 z) {
  u32 u = __float_as_uint(v);
  u = (u & 0x80000000u) ? ~u : (u | 0x80000000u);
  return ((unsigned long long)u << 32) | (unsigned long long)(0xFFFFFFFFu - z);
}
__device__ __forceinline__ float unpack_val(unsigned long long k) {
  u32 u = (u32)(k >> 32);
  u = (u & 0x80000000u) ? (u & 0x7FFFFFFFu) : ~u;
  return __uint_as_float(u);
}

// ---- K0a: diagonal / self-loops (bits zeroed by memset beforehand) ----
__global__ void k_init_adj(u32* bits, u32* deg, u16* adjl) {
  int z = blockIdx.x * blockDim.x + threadIdx.x;
  if (z >= ZZ) return;
  bits[(size_t)z * 128 + (z >> 5)] = 1u << (z & 31);
  deg[z] = 1;
  adjl[(size_t)z * ADJ_STRIDE] = (u16)z;
}

// ---- K0b: scatter edges (deduped via bitmask old-value) ----
__global__ void k_edges(const int* ei, u32* bits, u32* deg, u16* adjl) {
  int e = blockIdx.x * blockDim.x + threadIdx.x;
  if (e >= EE) return;
  int u = ei[e], v = ei[EE + e];
#pragma unroll
  for (int dir = 0; dir < 2; dir++) {
    int a = dir ? v : u, b = dir ? u : v;
    u32 bit = 1u << (b & 31);
    u32 old = atomicOr(&bits[(size_t)a * 128 + (b >> 5)], bit);
    if (!(old & bit)) {
      u32 p = atomicAdd(&deg[a], 1u);
      if (p < ADJ_STRIDE) adjl[(size_t)a * ADJ_STRIDE + p] = (u16)b;
    }
  }
}

// ---- K1: c = pa@W1[:512]+b1, w = W1[512] ----
__global__ void k_cvec(const float* pa, const float* W1, const float* b1,
                       float* cvec, float* wvec) {
  __shared__ float pal[512];
  int tid = threadIdx.x;  // 128
  for (int i = tid; i < 512; i += 128) pal[i] = pa[i];
  __syncthreads();
  float acc = b1[tid];
  for (int i = 0; i < 512; i++) acc = fmaf(pal[i], W1[(size_t)i * 128 + tid], acc);
  cvec[tid] = acc;
  wvec[tid] = W1[512 * 128 + tid];
}

// ---- K2: h2[t][j] = relu( relu(c + t*w) @ W2 + b2 ) ----
__global__ __launch_bounds__(256) void k_h2(const float* times, const float* W2,
                                            const float* b2, const float* cvec,
                                            const float* wvec, float* h2) {
  __shared__ float W2T[64][132];   // [j][i], padded
  __shared__ float h1b[4][128];
  __shared__ float cl[128], wl[128], b2l[64];
  int tid = threadIdx.x;
  for (int idx = tid; idx < 128 * 64; idx += 256) {
    int i = idx >> 6, j = idx & 63;
    W2T[j][i] = W2[idx];
  }
  if (tid < 128) { cl[tid] = cvec[tid]; wl[tid] = wvec[tid]; }
  else if (tid < 192) b2l[tid - 128] = b2[tid - 128];
  __syncthreads();
  int w = tid >> 6, lane = tid & 63;
  int t = blockIdx.x * 4 + w;
  float tv = times[t];
  h1b[w][lane]      = fmaxf(fmaf(tv, wl[lane],      cl[lane]),      0.f);
  h1b[w][lane + 64] = fmaxf(fmaf(tv, wl[lane + 64], cl[lane + 64]), 0.f);
  __syncthreads();
  float acc = b2l[lane];
  const float4* hr = (const float4*)&h1b[w][0];
  const float4* Wr = (const float4*)&W2T[lane][0];
#pragma unroll
  for (int i4 = 0; i4 < 32; i4++) {
    float4 a = hr[i4], bb = Wr[i4];
    acc += a.x * bb.x; acc += a.y * bb.y; acc += a.z * bb.z; acc += a.w * bb.w;
  }
  acc = fmaxf(acc, 0.f);
  h2[(size_t)t * 64 + lane] = acc;
}

// ---- K3: raw = h2@W3 + b3 -> d_out ; fused per-row global (max, argmax) ----
__global__ __launch_bounds__(256) void k_raw(const float* h2, const float* W3,
                                             const float* b3, float* out,
                                             unsigned long long* gmkey) {
  __shared__ float w3t[64][128];
  __shared__ float h2t[64][68];   // transposed, padded
  int tid = threadIdx.x;
  int zblk = blockIdx.x & 31, tblk = blockIdx.x >> 5;
  int z0 = zblk * 128, t0 = tblk * 64;
#pragma unroll
  for (int it = 0; it < 8; it++) {
    int f4 = tid + it * 256;                 // 2048 float4 = 8192 f32
    int k = f4 >> 5, jj = (f4 & 31) * 4;
    float4 wv = *(const float4*)(W3 + (size_t)k * ZZ + z0 + jj);
    *(float4*)&w3t[k][jj] = wv;
  }
#pragma unroll
  for (int it = 0; it < 4; it++) {
    int f4 = tid + it * 256;                 // 1024 float4 = 4096 f32
    int r = f4 >> 4, kk = (f4 & 15) * 4;
    float4 h = *(const float4*)(h2 + (size_t)(t0 + r) * 64 + kk);
    h2t[kk + 0][r] = h.x; h2t[kk + 1][r] = h.y;
    h2t[kk + 2][r] = h.z; h2t[kk + 3][r] = h.w;
  }
  __syncthreads();
  int lane = tid & 63, tg = tid >> 6;
  float acc[16][2];
#pragma unroll
  for (int r = 0; r < 16; r++) { acc[r][0] = 0.f; acc[r][1] = 0.f; }
  for (int k = 0; k < 64; k++) {
    float2 bw = *(const float2*)&w3t[k][lane * 2];
#pragma unroll
    for (int q = 0; q < 4; q++) {
      float4 a = *(const float4*)&h2t[k][tg * 16 + q * 4];
      acc[q*4+0][0] += a.x * bw.x; acc[q*4+0][1] += a.x * bw.y;
      acc[q*4+1][0] += a.y * bw.x; acc[q*4+1][1] += a.y * bw.y;
      acc[q*4+2][0] += a.z * bw.x; acc[q*4+2][1] += a.z * bw.y;
      acc[q*4+3][0] += a.w * bw.x; acc[q*4+3][1] += a.w * bw.y;
    }
  }
  int z = z0 + lane * 2;
  float2 b3v = *(const float2*)(b3 + z);
#pragma unroll
  for (int r = 0; r < 16; r++) {
    int t = t0 + tg * 16 + r;
    float v0 = acc[r][0] + b3v.x, v1 = acc[r][1] + b3v.y;
    float2 st; st.x = v0; st.y = v1;
    *(float2*)(out + (size_t)t * ZZ + z) = st;
    unsigned long long key = packkey(v0, (u32)z);
    unsigned long long k1  = packkey(v1, (u32)(z + 1));
    if (k1 > key) key = k1;
#pragma unroll
    for (int off = 32; off >= 1; off >>= 1) {
      unsigned long long o = __shfl_xor(key, off);
      if (o > key) key = o;
    }
    if (lane == 0) atomicMax(&gmkey[t], key);
  }
}

// ---- K4: per-block composed transition maps with image-dedup ----
__global__ __launch_bounds__(256) void k_stage1(const float* raw, const u16* adjl,
                                                const u32* deg,
                                                const unsigned long long* gmkey,
                                                u16* G) {
  __shared__ float row[2][ZZ];
  __shared__ u16 I[ZZ];
  __shared__ u16 ev[ZZ];
  __shared__ u16 U[ZZ];
  __shared__ u32 markw[ZZ / 4];
  __shared__ u32 mcnt;
  __shared__ float gmv_s;
  __shared__ u32 gmi_s;
  int tid = threadIdx.x;
  int b = blockIdx.x, t0 = b * LBLK;
  u8* markb = (u8*)markw;
  for (int j = tid; j < ZZ; j += 256) I[j] = (u16)j;
  {
    const float4* src = (const float4*)(raw + (size_t)t0 * ZZ);
    float4 s0 = src[tid], s1 = src[tid + 256], s2 = src[tid + 512], s3 = src[tid + 768];
    float4* dst = (float4*)row[0];
    dst[tid] = s0; dst[tid + 256] = s1; dst[tid + 512] = s2; dst[tid + 768] = s3;
  }
  __syncthreads();
  int lane = tid & 63;
  unsigned long long lmask = ((unsigned long long)1 << lane) - 1ull;
  for (int i = 0; i < LBLK; i++) {
    int t = t0 + i, cur = i & 1;
    int tn = (t + 1 < TT) ? t + 1 : t;
    const float4* srcn = (const float4*)(raw + (size_t)tn * ZZ);
    float4 p0 = srcn[tid], p1 = srcn[tid + 256], p2 = srcn[tid + 512], p3 = srcn[tid + 768];
    if (tid == 0) {
      unsigned long long k = gmkey[t];
      gmv_s = unpack_val(k) - PEN;
      gmi_s = 0xFFFFFFFFu - (u32)k;
    }
    int m;
    if (i == 0) {
      for (int j = tid; j < ZZ; j += 256) U[j] = (u16)j;
      m = ZZ;
      __syncthreads();
    } else {
      for (int j = tid; j < ZZ / 4; j += 256) markw[j] = 0;
      if (tid == 255) mcnt = 0;
      __syncthreads();
      for (int j = tid; j < ZZ; j += 256) markb[I[j]] = 1;
      __syncthreads();
      for (int ch = 0; ch < 16; ch++) {
        int s = ch * 256 + tid;
        bool pred = markb[s] != 0;
        unsigned long long msk = __ballot(pred ? 1 : 0);
        u32 cnt = (u32)__popcll(msk);
        u32 base = 0;
        if (lane == 0 && cnt) base = atomicAdd(&mcnt, cnt);
        base = __shfl(base, 0);
        if (pred) U[base + (u32)__popcll(msk & lmask)] = (u16)s;
      }
      __syncthreads();
      m = mcnt;
    }
    float gv = gmv_s; u32 gi = gmi_s;
    const float* r = row[cur];
    for (int u = tid; u < m; u += 256) {
      int s = U[u];
      int d = (int)deg[s]; if (d > ADJ_STRIDE) d = ADJ_STRIDE;
      const u64* alq = (const u64*)(adjl + (size_t)s * ADJ_STRIDE);
      float bv = -3.402823466e38f; u32 bi = 0xFFFFFFFFu;
      int nch = (d + 3) >> 2;
      for (int c = 0; c < nch; c++) {
        u64 chv = alq[c];
#pragma unroll
        for (int e2 = 0; e2 < 4; e2++) {
          int k = c * 4 + e2;
          if (k < d) {
            u32 nb = (u32)((chv >> (16 * e2)) & 0xFFFFu);
            float v = r[nb];
            if (v > bv || (v == bv && nb < bi)) { bv = v; bi = nb; }
          }
        }
      }
      if (gv > bv || (gv == bv && gi < bi)) bi = gi;
      ev[s] = (u16)bi;
    }
    __syncthreads();
    for (int j = tid; j < ZZ; j += 256) I[j] = ev[I[j]];
    __syncthreads();
    {
      float4* dst = (float4*)row[cur ^ 1];
      dst[tid] = p0; dst[tid + 256] = p1; dst[tid + 512] = p2; dst[tid + 768] = p3;
    }
    __syncthreads();
  }
  for (int j = tid; j < ZZ; j += 256) G[(size_t)b * ZZ + j] = I[j];
}

// ---- K5a: compose groups of 16 block-maps into super maps ----
__global__ __launch_bounds__(256) void k_super(const u16* G, u16* H) {
  int g = blockIdx.x, tid = threadIdx.x;
  u32 v[16];
#pragma unroll
  for (int q = 0; q < 16; q++) v[q] = G[(size_t)(g * 16) * ZZ + tid + q * 256];
  for (int k = 1; k < 16; k++) {
    const u16* Gk = G + (size_t)(g * 16 + k) * ZZ;
#pragma unroll
    for (int q = 0; q < 16; q++) v[q] = Gk[v[q]];
  }
#pragma unroll
  for (int q = 0; q < 16; q++) H[(size_t)g * ZZ + tid + q * 256] = (u16)v[q];
}

// ---- K5b: chase super maps then per-group block maps -> block start states ----
__global__ __launch_bounds__(1024) void k_chase(const u16* G, const u16* H, u32* sb) {
  __shared__ u32 ug[16];
  int tid = threadIdx.x;
  if (tid == 0) {
    u32 s = 0;
    for (int g = 0; g < 16; g++) { ug[g] = s; s = H[(size_t)g * ZZ + s]; }
  }
  __syncthreads();
  int w = tid >> 6;
  if ((tid & 63) == 0) {
    u32 s = ug[w];
    for (int k = 0; k < 16; k++) {
      int b = w * 16 + k;
      sb[b] = s;
      s = G[(size_t)b * ZZ + s];
    }
  }
}

// ---- K6: per-block replay -> cur[t] ----
__global__ __launch_bounds__(256) void k_replay(const float* raw, const u16* adjl,
                                                const u32* deg,
                                                const unsigned long long* gmkey,
                                                const u32* sb, u32* curz) {
  __shared__ float row[2][ZZ];
  __shared__ u32 s_sh;
  int tid = threadIdx.x;
  int b = blockIdx.x, t0 = b * LBLK;
  if (tid == 0) s_sh = sb[b];
  {
    const float4* src = (const float4*)(raw + (size_t)t0 * ZZ);
    float4 s0 = src[tid], s1 = src[tid + 256], s2 = src[tid + 512], s3 = src[tid + 768];
    float4* dst = (float4*)row[0];
    dst[tid] = s0; dst[tid + 256] = s1; dst[tid + 512] = s2; dst[tid + 768] = s3;
  }
  __syncthreads();
  for (int i = 0; i < LBLK; i++) {
    int t = t0 + i, cur = i & 1;
    int tn = (t + 1 < TT) ? t + 1 : t;
    const float4* srcn = (const float4*)(raw + (size_t)tn * ZZ);
    float4 p0 = srcn[tid], p1 = srcn[tid + 256], p2 = srcn[tid + 512], p3 = srcn[tid + 768];
    if (tid < 64) {
      u32 ss = s_sh;
      int d = (int)deg[ss]; if (d > ADJ_STRIDE) d = ADJ_STRIDE;
      const u16* al = adjl + (size_t)ss * ADJ_STRIDE;
      float bv = -3.402823466e38f; u32 bi = 0xFFFFFFFFu;
      if (tid < d)      { u32 nb = al[tid];      float v = row[cur][nb]; bv = v; bi = nb; }
      if (tid + 64 < d) { u32 nb = al[tid + 64]; float v = row[cur][nb];
        if (v > bv || (v == bv && nb < bi)) { bv = v; bi = nb; } }
#pragma unroll
      for (int off = 32; off >= 1; off >>= 1) {
        float ov = __shfl_xor(bv, off);
        u32 oi  = __shfl_xor(bi, off);
        if (ov > bv || (ov == bv && oi < bi)) { bv = ov; bi = oi; }
      }
      if (tid == 0) {
        unsigned long long kk = gmkey[t];
        float gv = unpack_val(kk) - PEN;
        u32 gi = 0xFFFFFFFFu - (u32)kk;
        if (gv > bv || (gv == bv && gi < bi)) bi = gi;
        curz[t] = ss;
        s_sh = bi;
      }
    }
    __syncthreads();
    {
      float4* dst = (float4*)row[cur ^ 1];
      dst[tid] = p0; dst[tid + 256] = p1; dst[tid + 512] = p2; dst[tid + 768] = p3;
    }
    __syncthreads();
  }
}

// ---- K7: out[t][z] = raw - 10*(1 - adj[cur[t]][z]) in place ----
__global__ __launch_bounds__(256) void k_out(float* out, const u32* curz, const u32* bits) {
  int t = blockIdx.x, tid = threadIdx.x;
  u32 c = curz[t];
  u32 w = bits[(size_t)c * 128 + (tid >> 1)];
  u32 half = (w >> ((tid & 1) * 16)) & 0xFFFFu;
  float* p = out + (size_t)t * ZZ + tid * 16;
#pragma unroll
  for (int q = 0; q < 4; q++) {
    float4 a = *(float4*)(p + q * 4);
    a.x -= ((half >> (q * 4 + 0)) & 1) ? 0.f : PEN;
    a.y -= ((half >> (q * 4 + 1)) & 1) ? 0.f : PEN;
    a.z -= ((half >> (q * 4 + 2)) & 1) ? 0.f : PEN;
    a.w -= ((half >> (q * 4 + 3)) & 1) ? 0.f : PEN;
    *(float4*)(p + q * 4) = a;
  }
}

extern "C" void kernel_launch(void* const* d_in, const int* in_sizes, int n_in,
                              void* d_out, int out_size, void* d_ws, size_t ws_size,
                              hipStream_t stream) {
  const float* pa    = (const float*)d_in[0];
  const float* times = (const float*)d_in[1];
  const int*   ei    = (const int*)d_in[3];
  const float* W1    = (const float*)d_in[4];
  const float* b1    = (const float*)d_in[5];
  const float* W2    = (const float*)d_in[6];
  const float* b2    = (const float*)d_in[7];
  const float* W3    = (const float*)d_in[8];
  const float* b3    = (const float*)d_in[9];
  float* out = (float*)d_out;
  char* ws = (char*)d_ws;

  u32* bits = (u32*)(ws + WS_BITS);
  unsigned long long* gmkey = (unsigned long long*)(ws + WS_GMKEY);
  u32* deg  = (u32*)(ws + WS_DEG);
  u16* adjl = (u16*)(ws + WS_ADJL);
  float* cvec = (float*)(ws + WS_CVEC);
  float* wvec = (float*)(ws + WS_WVEC);
  float* h2   = (float*)(ws + WS_H2);
  u16* G = (u16*)(ws + WS_G);
  u16* H = (u16*)(ws + WS_H);
  u32* sb   = (u32*)(ws + WS_SB);
  u32* curz = (u32*)(ws + WS_CUR);

  hipMemsetAsync(ws, 0, 0x220000, stream);  // bits + gmkey
  hipLaunchKernelGGL(k_init_adj, dim3(16), dim3(256), 0, stream, bits, deg, adjl);
  hipLaunchKernelGGL(k_edges, dim3(EE / 256), dim3(256), 0, stream, ei, bits, deg, adjl);
  hipLaunchKernelGGL(k_cvec, dim3(1), dim3(128), 0, stream, pa, W1, b1, cvec, wvec);
  hipLaunchKernelGGL(k_h2, dim3(TT / 4), dim3(256), 0, stream, times, W2, b2, cvec, wvec, h2);
  hipLaunchKernelGGL(k_raw, dim3(8192), dim3(256), 0, stream, h2, W3, b3, out, gmkey);
  hipLaunchKernelGGL(k_stage1, dim3(NBLK), dim3(256), 0, stream, out, adjl, deg, gmkey, G);
  hipLaunchKernelGGL(k_super, dim3(16), dim3(256), 0, stream, G, H);
  hipLaunchKernelGGL(k_chase, dim3(1), dim3(1024), 0, stream, G, H, sb);
  hipLaunchKernelGGL(k_replay, dim3(NBLK), dim3(256), 0, stream, out, adjl, deg, gmkey, sb, curz);
  hipLaunchKernelGGL(k_out, dim3(TT), dim3(256), 0, stream, out, curz, bits);
}

// Round 2
// 583.460 us; speedup vs baseline: 2.0337x; 2.0337x over previous
//
#include <hip/hip_runtime.h>
#include <hip/hip_bf16.h>
#include <stdint.h>

typedef uint16_t u16;
typedef uint32_t u32;
typedef uint64_t u64;
typedef unsigned char u8;

#define TT 16384
#define ZZ 4096
#define EE 65536
#define LBLK 32
#define NBLK 512          // TT / LBLK
#define NSUP 32           // NBLK / 16
#define SUPW 16
#define ADJ_STRIDE 80     // u16 entries per adjacency row (max degree ~60 w.h.p.)
#define PEN 10.0f

// ---- ws layout (bytes) ----
#define WS_BITS   0x000000   // u32[4096*128]  2 MB   adjacency bitmask
#define WS_GMKEY  0x200000   // u64[16384]     128 KB packed global (max,argmax) per row
#define WS_DEG    0x220000   // u32[4096]
#define WS_ADJL   0x224000   // u16[4096*80]   640 KB CSR lists (padded to mult of 4)
#define WS_CVEC   0x2C4000   // f32[128]
#define WS_WVEC   0x2C4200   // f32[128]
#define WS_H2     0x2C4400   // f32[16384*64]  4 MB   (dead after k_raw)
#define WS_G      WS_H2      // u16[512*4096]  4 MB   aliases h2
#define WS_H      0x6C4400   // u16[32*4096]   256 KB super maps
#define WS_SB     0x704400   // u32[512]       block-start states

// monotone (value, min-index) packing: bigger key == larger value, then smaller z
__device__ __forceinline__ unsigned long long packkey(float v, u32 z) {
  u32 u = __float_as_uint(v);
  u = (u & 0x80000000u) ? ~u : (u | 0x80000000u);
  return ((unsigned long long)u << 32) | (unsigned long long)(0xFFFFFFFFu - z);
}
__device__ __forceinline__ float unpack_val(unsigned long long k) {
  u32 u = (u32)(k >> 32);
  u = (u & 0x80000000u) ? (u & 0x7FFFFFFFu) : ~u;
  return __uint_as_float(u);
}

// ---- K0a: diagonal / self-loops (bits zeroed by memset beforehand) ----
__global__ void k_init_adj(u32* bits, u32* deg, u16* adjl) {
  int z = blockIdx.x * blockDim.x + threadIdx.x;
  if (z >= ZZ) return;
  bits[(size_t)z * 128 + (z >> 5)] = 1u << (z & 31);
  deg[z] = 1;
  adjl[(size_t)z * ADJ_STRIDE] = (u16)z;
}

// ---- K0b: scatter edges (deduped via bitmask old-value) ----
__global__ void k_edges(const int* ei, u32* bits, u32* deg, u16* adjl) {
  int e = blockIdx.x * blockDim.x + threadIdx.x;
  if (e >= EE) return;
  int u = ei[e], v = ei[EE + e];
#pragma unroll
  for (int dir = 0; dir < 2; dir++) {
    int a = dir ? v : u, b = dir ? u : v;
    u32 bit = 1u << (b & 31);
    u32 old = atomicOr(&bits[(size_t)a * 128 + (b >> 5)], bit);
    if (!(old & bit)) {
      u32 p = atomicAdd(&deg[a], 1u);
      if (p < ADJ_STRIDE) adjl[(size_t)a * ADJ_STRIDE + p] = (u16)b;
    }
  }
}

// ---- K0c: pad each adjacency row to a multiple of 4 with duplicate self ----
__global__ void k_pad(const u32* deg, u16* adjl) {
  int z = blockIdx.x * blockDim.x + threadIdx.x;
  if (z >= ZZ) return;
  int d = (int)deg[z]; if (d > ADJ_STRIDE) d = ADJ_STRIDE;
  int dp = (d + 3) & ~3;
  for (int k = d; k < dp; k++) adjl[(size_t)z * ADJ_STRIDE + k] = (u16)z;
}

// ---- K1: c = pa@W1[:512]+b1, w = W1[512] ----
__global__ void k_cvec(const float* pa, const float* W1, const float* b1,
                       float* cvec, float* wvec) {
  __shared__ float pal[512];
  int tid = threadIdx.x;  // 128
  for (int i = tid; i < 512; i += 128) pal[i] = pa[i];
  __syncthreads();
  float acc = b1[tid];
  for (int i = 0; i < 512; i++) acc = fmaf(pal[i], W1[(size_t)i * 128 + tid], acc);
  cvec[tid] = acc;
  wvec[tid] = W1[512 * 128 + tid];
}

// ---- K2: h2[t][j] = relu( relu(c + t*w) @ W2 + b2 ) ----
__global__ __launch_bounds__(256) void k_h2(const float* times, const float* W2,
                                            const float* b2, const float* cvec,
                                            const float* wvec, float* h2) {
  __shared__ float W2T[64][132];   // [j][i], padded
  __shared__ float h1b[4][128];
  __shared__ float cl[128], wl[128], b2l[64];
  int tid = threadIdx.x;
  for (int idx = tid; idx < 128 * 64; idx += 256) {
    int i = idx >> 6, j = idx & 63;
    W2T[j][i] = W2[idx];
  }
  if (tid < 128) { cl[tid] = cvec[tid]; wl[tid] = wvec[tid]; }
  else if (tid < 192) b2l[tid - 128] = b2[tid - 128];
  __syncthreads();
  int w = tid >> 6, lane = tid & 63;
  int t = blockIdx.x * 4 + w;
  float tv = times[t];
  h1b[w][lane]      = fmaxf(fmaf(tv, wl[lane],      cl[lane]),      0.f);
  h1b[w][lane + 64] = fmaxf(fmaf(tv, wl[lane + 64], cl[lane + 64]), 0.f);
  __syncthreads();
  float acc = b2l[lane];
  const float4* hr = (const float4*)&h1b[w][0];
  const float4* Wr = (const float4*)&W2T[lane][0];
#pragma unroll
  for (int i4 = 0; i4 < 32; i4++) {
    float4 a = hr[i4], bb = Wr[i4];
    acc += a.x * bb.x; acc += a.y * bb.y; acc += a.z * bb.z; acc += a.w * bb.w;
  }
  acc = fmaxf(acc, 0.f);
  h2[(size_t)t * 64 + lane] = acc;
}

// ---- K3: raw = h2@W3 + b3 -> d_out ; fused per-row global (max, argmax) ----
// 256 thr; tile 64t x 128z; thread = 8t x 4z; 3x b128 LDS reads per k, 32 FMA.
__global__ __launch_bounds__(256) void k_raw(const float* h2, const float* W3,
                                             const float* b3, float* out,
                                             unsigned long long* gmkey) {
  __shared__ float w3t[64][128];   // 32 KB
  __shared__ float h2t[64][72];    // 18 KB, transposed [k][t]
  int tid = threadIdx.x;
  int zblk = blockIdx.x & 31, tblk = blockIdx.x >> 5;
  int z0 = zblk * 128, t0 = tblk * 64;
#pragma unroll
  for (int it = 0; it < 8; it++) {
    int f4 = tid + it * 256;                 // 2048 float4 = 8192 f32
    int k = f4 >> 5, jj = (f4 & 31) * 4;
    *(float4*)&w3t[k][jj] = *(const float4*)(W3 + (size_t)k * ZZ + z0 + jj);
  }
#pragma unroll
  for (int it = 0; it < 4; it++) {
    int f4 = tid + it * 256;                 // 1024 float4 = 4096 f32
    int r = f4 >> 4, kk = (f4 & 15) * 4;
    float4 h = *(const float4*)(h2 + (size_t)(t0 + r) * 64 + kk);
    h2t[kk + 0][r] = h.x; h2t[kk + 1][r] = h.y;
    h2t[kk + 2][r] = h.z; h2t[kk + 3][r] = h.w;
  }
  __syncthreads();
  int zq = tid & 31, tq = tid >> 5;
  float4 acc[8];
#pragma unroll
  for (int r = 0; r < 8; r++) acc[r] = make_float4(0.f, 0.f, 0.f, 0.f);
  for (int k = 0; k < 64; k++) {
    float4 w = *(const float4*)&w3t[k][zq * 4];
    float4 hA = *(const float4*)&h2t[k][tq * 8];
    float4 hB = *(const float4*)&h2t[k][tq * 8 + 4];
    acc[0].x += hA.x * w.x; acc[0].y += hA.x * w.y; acc[0].z += hA.x * w.z; acc[0].w += hA.x * w.w;
    acc[1].x += hA.y * w.x; acc[1].y += hA.y * w.y; acc[1].z += hA.y * w.z; acc[1].w += hA.y * w.w;
    acc[2].x += hA.z * w.x; acc[2].y += hA.z * w.y; acc[2].z += hA.z * w.z; acc[2].w += hA.z * w.w;
    acc[3].x += hA.w * w.x; acc[3].y += hA.w * w.y; acc[3].z += hA.w * w.z; acc[3].w += hA.w * w.w;
    acc[4].x += hB.x * w.x; acc[4].y += hB.x * w.y; acc[4].z += hB.x * w.z; acc[4].w += hB.x * w.w;
    acc[5].x += hB.y * w.x; acc[5].y += hB.y * w.y; acc[5].z += hB.y * w.z; acc[5].w += hB.y * w.w;
    acc[6].x += hB.z * w.x; acc[6].y += hB.z * w.y; acc[6].z += hB.z * w.z; acc[6].w += hB.z * w.w;
    acc[7].x += hB.w * w.x; acc[7].y += hB.w * w.y; acc[7].z += hB.w * w.z; acc[7].w += hB.w * w.w;
  }
  int z = z0 + zq * 4;
  float4 b3v = *(const float4*)(b3 + z);
  int lane = tid & 63;
#pragma unroll
  for (int r = 0; r < 8; r++) {
    int t = t0 + tq * 8 + r;
    float4 v;
    v.x = acc[r].x + b3v.x; v.y = acc[r].y + b3v.y;
    v.z = acc[r].z + b3v.z; v.w = acc[r].w + b3v.w;
    *(float4*)(out + (size_t)t * ZZ + z) = v;
    unsigned long long key = packkey(v.x, (u32)z);
    unsigned long long k2;
    k2 = packkey(v.y, (u32)(z + 1)); if (k2 > key) key = k2;
    k2 = packkey(v.z, (u32)(z + 2)); if (k2 > key) key = k2;
    k2 = packkey(v.w, (u32)(z + 3)); if (k2 > key) key = k2;
#pragma unroll
    for (int off = 16; off >= 1; off >>= 1) {
      unsigned long long o = __shfl_xor(key, off);
      if (o > key) key = o;
    }
    if ((lane & 31) == 0) atomicMax(&gmkey[t], key);
  }
}

// ---- K4: per-block composed transition maps, O(m) incremental image dedup ----
__global__ __launch_bounds__(512) void k_stage1(const float* raw, const u16* adjl,
                                                const u32* deg,
                                                const unsigned long long* gmkey,
                                                u16* G) {
  __shared__ float row[2][ZZ];    // 32 KB
  __shared__ u16 I[ZZ];           // 8 KB
  __shared__ u16 ev[ZZ];          // 8 KB
  __shared__ u16 U[2][ZZ];        // 16 KB worklists (image), double-buffered
  __shared__ u32 markw[128];      // 4096-bit membership mask
  __shared__ u32 mcnt2[2];
  __shared__ u8  degl[ZZ];        // 4 KB clipped degrees
  __shared__ unsigned long long gmk[LBLK];
  int tid = threadIdx.x;
  int b = blockIdx.x, t0 = b * LBLK;
  for (int j = tid; j < ZZ; j += 512) {
    I[j] = (u16)j;
    U[0][j] = (u16)j;
    u32 d = deg[j];
    degl[j] = (u8)(d > ADJ_STRIDE ? ADJ_STRIDE : d);
  }
  if (tid < LBLK) gmk[tid] = gmkey[t0 + tid];
  {
    const float4* src = (const float4*)(raw + (size_t)t0 * ZZ);
    float4* dst = (float4*)row[0];
    dst[tid] = src[tid]; dst[tid + 512] = src[tid + 512];
  }
  __syncthreads();
  int lane = tid & 63;
  u64 lmask = (((u64)1) << lane) - 1ull;
  int m = ZZ, pb = 0, cur = 0;
  for (int i = 0; i < LBLK; i++) {
    int t = t0 + i;
    // ---- phase A: clear mark, prefetch next row, evaluate f_t on image ----
    int tn = t + 1; if (tn >= TT) tn = TT - 1;
    const float4* srcn = (const float4*)(raw + (size_t)tn * ZZ);
    float4 p0 = srcn[tid], p1 = srcn[tid + 512];
    if (tid < 128) markw[tid] = 0;
    if (tid == 128) mcnt2[pb ^ 1] = 0;
    unsigned long long gk = gmk[i];
    float gv = unpack_val(gk) - PEN;
    u32 gi = 0xFFFFFFFFu - (u32)gk;
    const float* r = row[cur];
    for (int u = tid; u < m; u += 512) {
      int s = U[pb][u];
      int d = degl[s];
      const u64* alq = (const u64*)(adjl + (size_t)s * ADJ_STRIDE);
      float bv = gv; u32 bi = gi;
      int nch = (d + 3) >> 2;
      for (int c = 0; c < nch; c++) {
        u64 chv = alq[c];
        u32 n0 = (u32)(chv & 0xFFFFu);
        u32 n1 = (u32)((chv >> 16) & 0xFFFFu);
        u32 n2 = (u32)((chv >> 32) & 0xFFFFu);
        u32 n3 = (u32)(chv >> 48);
        float v0 = r[n0], v1 = r[n1], v2 = r[n2], v3 = r[n3];
        if (v0 > bv || (v0 == bv && n0 < bi)) { bv = v0; bi = n0; }
        if (v1 > bv || (v1 == bv && n1 < bi)) { bv = v1; bi = n1; }
        if (v2 > bv || (v2 == bv && n2 < bi)) { bv = v2; bi = n2; }
        if (v3 > bv || (v3 == bv && n3 < bi)) { bv = v3; bi = n3; }
      }
      ev[s] = (u16)bi;
    }
    __syncthreads();
    // ---- phase B: compose I, build deduped new image, store next row ----
#pragma unroll
    for (int q = 0; q < 8; q++) {
      int j = tid + q * 512;
      I[j] = ev[I[j]];
    }
    for (int u = tid; u < m; u += 512) {
      int s = U[pb][u];
      u32 ns = ev[s];
      u32 wi = ns >> 5, bit = 1u << (ns & 31);
      u32 old = atomicOr(&markw[wi], bit);
      bool isnew = !(old & bit);
      u64 msk = __ballot(isnew ? 1 : 0);
      u32 base = 0;
      if (lane == 0) base = msk ? atomicAdd(&mcnt2[pb ^ 1], (u32)__popcll(msk)) : 0u;
      base = __shfl(base, 0);
      if (isnew) U[pb ^ 1][base + (u32)__popcll(msk & lmask)] = (u16)ns;
    }
    {
      float4* dst = (float4*)row[cur ^ 1];
      dst[tid] = p0; dst[tid + 512] = p1;
    }
    __syncthreads();
    m = (int)mcnt2[pb ^ 1];
    pb ^= 1; cur ^= 1;
  }
  for (int j = tid; j < ZZ; j += 512) G[(size_t)b * ZZ + j] = I[j];
}

// ---- K5a: compose groups of 16 block-maps into super maps ----
__global__ __launch_bounds__(256) void k_super(const u16* G, u16* H) {
  int g = blockIdx.x, tid = threadIdx.x;
  u32 v[16];
#pragma unroll
  for (int q = 0; q < 16; q++) v[q] = G[(size_t)(g * SUPW) * ZZ + tid + q * 256];
  for (int k = 1; k < SUPW; k++) {
    const u16* Gk = G + (size_t)(g * SUPW + k) * ZZ;
#pragma unroll
    for (int q = 0; q < 16; q++) v[q] = Gk[v[q]];
  }
#pragma unroll
  for (int q = 0; q < 16; q++) H[(size_t)g * ZZ + tid + q * 256] = (u16)v[q];
}

// ---- K5b: chase super maps then per-group block maps -> block start states ----
__global__ void k_chase(const u16* G, const u16* H, u32* sb) {
  __shared__ u32 ug[NSUP];
  int tid = threadIdx.x;  // 64
  if (tid == 0) {
    u32 s = 0;
    for (int g = 0; g < NSUP; g++) { ug[g] = s; s = H[(size_t)g * ZZ + s]; }
  }
  __syncthreads();
  if (tid < NSUP) {
    u32 s = ug[tid];
    for (int k = 0; k < SUPW; k++) {
      int b = tid * SUPW + k;
      sb[b] = s;
      s = G[(size_t)b * ZZ + s];
    }
  }
}

// ---- K6: per-block replay + fused penalty-adjusted output write (in place) ----
__global__ __launch_bounds__(512) void k_replay(float* out, const u16* adjl,
                                                const u32* deg,
                                                const unsigned long long* gmkey,
                                                const u32* sb, const u32* bits) {
  __shared__ float row[2][ZZ];   // 32 KB
  __shared__ u8 degl[ZZ];        // 4 KB
  __shared__ unsigned long long gmk[LBLK];
  __shared__ u32 s_arr[2];
  int tid = threadIdx.x;
  int b = blockIdx.x, t0 = b * LBLK;
  for (int j = tid; j < ZZ; j += 512) {
    u32 d = deg[j];
    degl[j] = (u8)(d > ADJ_STRIDE ? ADJ_STRIDE : d);
  }
  if (tid < LBLK) gmk[tid] = gmkey[t0 + tid];
  if (tid == 0) s_arr[0] = sb[b];
  {
    const float4* src = (const float4*)(out + (size_t)t0 * ZZ);
    float4* dst = (float4*)row[0];
    dst[tid] = src[tid]; dst[tid + 512] = src[tid + 512];
  }
  __syncthreads();
  for (int i = 0; i < LBLK; i++) {
    int t = t0 + i, cur = i & 1;
    u32 ss = s_arr[i & 1];
    int tn = t + 1; if (tn >= TT) tn = TT - 1;
    const float4* srcn = (const float4*)(out + (size_t)tn * ZZ);
    float4 p0 = srcn[tid], p1 = srcn[tid + 512];
    if (tid < 64) {                       // wave 0: next-state eval
      int d = degl[ss];
      const u16* al = adjl + (size_t)ss * ADJ_STRIDE;
      float bv = -3.402823466e38f; u32 bi = 0xFFFFFFFFu;
      if (tid < d)      { u32 nb = al[tid];      float v = row[cur][nb]; bv = v; bi = nb; }
      if (tid + 64 < d) { u32 nb = al[tid + 64]; float v = row[cur][nb];
        if (v > bv || (v == bv && nb < bi)) { bv = v; bi = nb; } }
#pragma unroll
      for (int off = 32; off >= 1; off >>= 1) {
        float ov = __shfl_xor(bv, off);
        u32 oi  = __shfl_xor(bi, off);
        if (ov > bv || (ov == bv && oi < bi)) { bv = ov; bi = oi; }
      }
      if (tid == 0) {
        unsigned long long kk = gmk[i];
        float gv = unpack_val(kk) - PEN;
        u32 gi = 0xFFFFFFFFu - (u32)kk;
        if (gv > bv || (gv == bv && gi < bi)) bi = gi;
        s_arr[(i + 1) & 1] = bi;
      }
    }
    __syncthreads();
    // phase B: penalty-adjusted output for row t + stage next row
#pragma unroll
    for (int q = 0; q < 2; q++) {
      int j = tid + q * 512;                       // float4 index 0..1023
      u32 wv = bits[(size_t)ss * 128 + (j >> 3)];
      u32 nib = (wv >> ((j & 7) * 4)) & 0xFu;
      float4 a = *(const float4*)&row[cur][j * 4];
      a.x -= (nib & 1) ? 0.f : PEN;
      a.y -= (nib & 2) ? 0.f : PEN;
      a.z -= (nib & 4) ? 0.f : PEN;
      a.w -= (nib & 8) ? 0.f : PEN;
      *(float4*)(out + (size_t)t * ZZ + j * 4) = a;
    }
    {
      float4* dst = (float4*)row[cur ^ 1];
      dst[tid] = p0; dst[tid + 512] = p1;
    }
    __syncthreads();
  }
}

extern "C" void kernel_launch(void* const* d_in, const int* in_sizes, int n_in,
                              void* d_out, int out_size, void* d_ws, size_t ws_size,
                              hipStream_t stream) {
  const float* pa    = (const float*)d_in[0];
  const float* times = (const float*)d_in[1];
  const int*   ei    = (const int*)d_in[3];
  const float* W1    = (const float*)d_in[4];
  const float* b1    = (const float*)d_in[5];
  const float* W2    = (const float*)d_in[6];
  const float* b2    = (const float*)d_in[7];
  const float* W3    = (const float*)d_in[8];
  const float* b3    = (const float*)d_in[9];
  float* out = (float*)d_out;
  char* ws = (char*)d_ws;

  u32* bits = (u32*)(ws + WS_BITS);
  unsigned long long* gmkey = (unsigned long long*)(ws + WS_GMKEY);
  u32* deg  = (u32*)(ws + WS_DEG);
  u16* adjl = (u16*)(ws + WS_ADJL);
  float* cvec = (float*)(ws + WS_CVEC);
  float* wvec = (float*)(ws + WS_WVEC);
  float* h2   = (float*)(ws + WS_H2);
  u16* G = (u16*)(ws + WS_G);
  u16* H = (u16*)(ws + WS_H);
  u32* sb   = (u32*)(ws + WS_SB);

  hipMemsetAsync(ws, 0, 0x220000, stream);  // bits + gmkey
  hipLaunchKernelGGL(k_init_adj, dim3(16), dim3(256), 0, stream, bits, deg, adjl);
  hipLaunchKernelGGL(k_edges, dim3(EE / 256), dim3(256), 0, stream, ei, bits, deg, adjl);
  hipLaunchKernelGGL(k_pad, dim3(16), dim3(256), 0, stream, deg, adjl);
  hipLaunchKernelGGL(k_cvec, dim3(1), dim3(128), 0, stream, pa, W1, b1, cvec, wvec);
  hipLaunchKernelGGL(k_h2, dim3(TT / 4), dim3(256), 0, stream, times, W2, b2, cvec, wvec, h2);
  hipLaunchKernelGGL(k_raw, dim3(8192), dim3(256), 0, stream, h2, W3, b3, out, gmkey);
  hipLaunchKernelGGL(k_stage1, dim3(NBLK), dim3(512), 0, stream, out, adjl, deg, gmkey, G);
  hipLaunchKernelGGL(k_super, dim3(NSUP), dim3(256), 0, stream, G, H);
  hipLaunchKernelGGL(k_chase, dim3(1), dim3(64), 0, stream, G, H, sb);
  hipLaunchKernelGGL(k_replay, dim3(NBLK), dim3(512), 0, stream, out, adjl, deg, gmkey, sb, bits);
}